// Round 1
// baseline (683.341 us; speedup 1.0000x reference)
//
#include <hip/hip_runtime.h>
#include <hip/hip_bf16.h>

#define B_ 8
#define N_ 2048
#define FIN_ 128
#define FO_ 64
#define ALPHA_ 0.2f
#define NEGINF_ -1000000000.0f

// ---------------------------------------------------------------------------
// K1: h_prime = h @ W  (B*N x FIN) x (FIN x FO), plus e_l = h'·a_l, e_r = h'·a_r
// One wave per 4 rows, lane = output column o. W staged in LDS (32KB).
// ---------------------------------------------------------------------------
__global__ __launch_bounds__(256) void k1_hprime(
    const float* __restrict__ h, const float* __restrict__ W,
    const float* __restrict__ a, float* __restrict__ hp,
    float* __restrict__ el, float* __restrict__ er)
{
    __shared__ float Wl[FIN_ * FO_];
    __shared__ float al[FO_], ar[FO_];
    __shared__ float hrow[4][4][FIN_];

    int tid = threadIdx.x;
    const float4* W4 = (const float4*)W;
    float4* Wl4 = (float4*)Wl;
#pragma unroll
    for (int i = 0; i < 8; ++i) Wl4[tid + 256 * i] = W4[tid + 256 * i];
    if (tid < FO_) { al[tid] = a[tid]; ar[tid] = a[FO_ + tid]; }

    int wave = tid >> 6, lane = tid & 63;
    int row0 = blockIdx.x * 16 + wave * 4;
#pragma unroll
    for (int rr = 0; rr < 4; ++rr) {
        hrow[wave][rr][lane]      = h[(size_t)(row0 + rr) * FIN_ + lane];
        hrow[wave][rr][lane + 64] = h[(size_t)(row0 + rr) * FIN_ + lane + 64];
    }
    __syncthreads();

    float acc0 = 0.f, acc1 = 0.f, acc2 = 0.f, acc3 = 0.f;
#pragma unroll 8
    for (int k = 0; k < FIN_; ++k) {
        float w = Wl[k * FO_ + lane];
        acc0 = fmaf(hrow[wave][0][k], w, acc0);
        acc1 = fmaf(hrow[wave][1][k], w, acc1);
        acc2 = fmaf(hrow[wave][2][k], w, acc2);
        acc3 = fmaf(hrow[wave][3][k], w, acc3);
    }

    float accs[4] = {acc0, acc1, acc2, acc3};
#pragma unroll
    for (int rr = 0; rr < 4; ++rr) {
        int row = row0 + rr;
        hp[(size_t)row * FO_ + lane] = accs[rr];
        float pl = accs[rr] * al[lane];
        float pr = accs[rr] * ar[lane];
#pragma unroll
        for (int off = 32; off; off >>= 1) {
            pl += __shfl_xor(pl, off);
            pr += __shfl_xor(pr, off);
        }
        if (lane == 0) { el[row] = pl; er[row] = pr; }
    }
}

// ---------------------------------------------------------------------------
// K2: masked softmax rows + write attention.
// Block = one row i; adj row staged once as LDS bitmask (256B), reused for
// all 8 batches. Wave w handles batches {w, w+4}; full score row lives in
// 32 VGPRs; two butterfly reductions (max, sum); one coalesced write pass.
// ---------------------------------------------------------------------------
__global__ __launch_bounds__(256) void k2_softmax(
    const int* __restrict__ adj, const float* __restrict__ el,
    const float* __restrict__ er, float* __restrict__ attn)
{
    __shared__ unsigned adjb[N_ / 32];
    int i = blockIdx.x;
    int tid = threadIdx.x, wave = tid >> 6, lane = tid & 63;

#pragma unroll
    for (int c = 0; c < 8; ++c) {
        int j = c * 256 + tid;
        unsigned long long msk = __ballot(adj[(size_t)i * N_ + j] > 0);
        if (lane == 0) {
            adjb[(j >> 5)]     = (unsigned)msk;
            adjb[(j >> 5) + 1] = (unsigned)(msk >> 32);
        }
    }
    __syncthreads();

    const float LOG2E = 1.44269504088896340736f;
#pragma unroll
    for (int bb = 0; bb < 2; ++bb) {
        int b = wave + bb * 4;
        float elv = el[(size_t)b * N_ + i];
        const float* erp = er + (size_t)b * N_;
        float* arow = attn + (size_t)b * N_ * N_ + (size_t)i * N_;

        float s[32];
        float m = -3.4e38f;
#pragma unroll
        for (int c = 0; c < 32; ++c) {
            int j = c * 64 + lane;
            float x = elv + erp[j];
            x = fmaxf(x, ALPHA_ * x);              // leaky_relu, alpha<1
            unsigned bit = (adjb[j >> 5] >> (j & 31)) & 1u;
            x = bit ? x : NEGINF_;
            s[c] = x;
            m = fmaxf(m, x);
        }
#pragma unroll
        for (int off = 32; off; off >>= 1) m = fmaxf(m, __shfl_xor(m, off));

        float sum = 0.f;
#pragma unroll
        for (int c = 0; c < 32; ++c) {
            float p = __builtin_amdgcn_exp2f((s[c] - m) * LOG2E);
            s[c] = p;
            sum += p;
        }
#pragma unroll
        for (int off = 32; off; off >>= 1) sum += __shfl_xor(sum, off);

        float inv = 1.0f / sum;
#pragma unroll
        for (int c = 0; c < 32; ++c) arow[(size_t)c * 64 + lane] = s[c] * inv;
    }
}

// ---------------------------------------------------------------------------
// K3: h_out = attn @ h_prime  (per batch: 2048x2048 · 2048x64), fp32 vector.
// Lane owns column o=lane → h' element is a per-lane register reused over 16
// rows. attn row data is wave-uniform → scalar loads (SMEM pipe), no LDS.
// bv double-buffer hides L2 latency of the h' stream (512KB/batch, L2-hot).
// ---------------------------------------------------------------------------
__global__ __launch_bounds__(256) void k3_pv(
    const float* __restrict__ attn, const float* __restrict__ hp,
    float* __restrict__ hout)
{
    int tid = threadIdx.x;
    int wave = __builtin_amdgcn_readfirstlane(tid >> 6);
    int lane = tid & 63;
    int b = blockIdx.y;
    int i0 = blockIdx.x * 64 + wave * 16;

    const float* Ab  = attn + (size_t)b * N_ * N_;
    const float* hpb = hp + (size_t)b * N_ * FO_ + lane;

    float acc[16];
#pragma unroll
    for (int r = 0; r < 16; ++r) acc[r] = 0.f;

    float bv0[16], bv1[16];
#pragma unroll
    for (int kk = 0; kk < 16; ++kk) bv0[kk] = hpb[(size_t)kk * FO_];

#pragma unroll 1
    for (int k0 = 0; k0 < N_ - 32; k0 += 32) {
        // prefetch next half
#pragma unroll
        for (int kk = 0; kk < 16; ++kk) bv1[kk] = hpb[(size_t)(k0 + 16 + kk) * FO_];
        // compute on bv0 (attn loads are wave-uniform -> s_load)
#pragma unroll
        for (int r = 0; r < 16; ++r) {
            const float* Ar = Ab + (size_t)(i0 + r) * N_ + k0;
#pragma unroll
            for (int kk = 0; kk < 16; ++kk) acc[r] = fmaf(Ar[kk], bv0[kk], acc[r]);
        }
#pragma unroll
        for (int kk = 0; kk < 16; ++kk) bv0[kk] = hpb[(size_t)(k0 + 32 + kk) * FO_];
#pragma unroll
        for (int r = 0; r < 16; ++r) {
            const float* Ar = Ab + (size_t)(i0 + r) * N_ + k0 + 16;
#pragma unroll
            for (int kk = 0; kk < 16; ++kk) acc[r] = fmaf(Ar[kk], bv1[kk], acc[r]);
        }
    }
    // tail: k0 = N_-32
    {
        int k0 = N_ - 32;
#pragma unroll
        for (int kk = 0; kk < 16; ++kk) bv1[kk] = hpb[(size_t)(k0 + 16 + kk) * FO_];
#pragma unroll
        for (int r = 0; r < 16; ++r) {
            const float* Ar = Ab + (size_t)(i0 + r) * N_ + k0;
#pragma unroll
            for (int kk = 0; kk < 16; ++kk) acc[r] = fmaf(Ar[kk], bv0[kk], acc[r]);
        }
#pragma unroll
        for (int r = 0; r < 16; ++r) {
            const float* Ar = Ab + (size_t)(i0 + r) * N_ + k0 + 16;
#pragma unroll
            for (int kk = 0; kk < 16; ++kk) acc[r] = fmaf(Ar[kk], bv1[kk], acc[r]);
        }
    }

    float* ob = hout + (size_t)b * N_ * FO_ + (size_t)i0 * FO_ + lane;
#pragma unroll
    for (int r = 0; r < 16; ++r) ob[(size_t)r * FO_] = acc[r];
}

// ---------------------------------------------------------------------------
extern "C" void kernel_launch(void* const* d_in, const int* in_sizes, int n_in,
                              void* d_out, int out_size, void* d_ws, size_t ws_size,
                              hipStream_t stream) {
    const float* h   = (const float*)d_in[0];
    const int*   adj = (const int*)d_in[1];
    const float* W   = (const float*)d_in[2];
    const float* a   = (const float*)d_in[3];

    float* hout = (float*)d_out;                                  // 8*2048*64
    float* attn = (float*)d_out + (size_t)B_ * N_ * FO_;          // 8*2048*2048

    float* hp = (float*)d_ws;                                     // 8*2048*64
    float* el = hp + (size_t)B_ * N_ * FO_;                       // 8*2048
    float* er = el + (size_t)B_ * N_;                             // 8*2048

    k1_hprime<<<1024, 256, 0, stream>>>(h, W, a, hp, el, er);
    k2_softmax<<<2048, 256, 0, stream>>>(adj, el, er, attn);
    k3_pv<<<dim3(N_ / 64, B_), 256, 0, stream>>>(attn, hp, hout);
}

// Round 3
// 362.643 us; speedup vs baseline: 1.8843x; 1.8843x over previous
//
#include <hip/hip_runtime.h>
#include <hip/hip_bf16.h>

#define B_ 8
#define N_ 2048
#define FIN_ 128
#define FO_ 64
#define ALPHA_ 0.2f
#define NEGINF_ -1000000000.0f
#define SPLIT_ 4
#define KSEG_ (N_ / SPLIT_)   // 512

// ---------------------------------------------------------------------------
// K1: h_prime = h @ W  (B*N x FIN) x (FIN x FO), plus e_l = h'·a_l, e_r = h'·a_r
// One wave per 4 rows, lane = output column o. W staged in LDS (32KB).
// ---------------------------------------------------------------------------
__global__ __launch_bounds__(256) void k1_hprime(
    const float* __restrict__ h, const float* __restrict__ W,
    const float* __restrict__ a, float* __restrict__ hp,
    float* __restrict__ el, float* __restrict__ er)
{
    __shared__ float Wl[FIN_ * FO_];
    __shared__ float al[FO_], ar[FO_];
    __shared__ float hrow[4][4][FIN_];

    int tid = threadIdx.x;
    const float4* W4 = (const float4*)W;
    float4* Wl4 = (float4*)Wl;
#pragma unroll
    for (int i = 0; i < 8; ++i) Wl4[tid + 256 * i] = W4[tid + 256 * i];
    if (tid < FO_) { al[tid] = a[tid]; ar[tid] = a[FO_ + tid]; }

    int wave = tid >> 6, lane = tid & 63;
    int row0 = blockIdx.x * 16 + wave * 4;
#pragma unroll
    for (int rr = 0; rr < 4; ++rr) {
        hrow[wave][rr][lane]      = h[(size_t)(row0 + rr) * FIN_ + lane];
        hrow[wave][rr][lane + 64] = h[(size_t)(row0 + rr) * FIN_ + lane + 64];
    }
    __syncthreads();

    float acc0 = 0.f, acc1 = 0.f, acc2 = 0.f, acc3 = 0.f;
#pragma unroll 8
    for (int k = 0; k < FIN_; ++k) {
        float w = Wl[k * FO_ + lane];
        acc0 = fmaf(hrow[wave][0][k], w, acc0);
        acc1 = fmaf(hrow[wave][1][k], w, acc1);
        acc2 = fmaf(hrow[wave][2][k], w, acc2);
        acc3 = fmaf(hrow[wave][3][k], w, acc3);
    }

    float accs[4] = {acc0, acc1, acc2, acc3};
#pragma unroll
    for (int rr = 0; rr < 4; ++rr) {
        int row = row0 + rr;
        hp[(size_t)row * FO_ + lane] = accs[rr];
        float pl = accs[rr] * al[lane];
        float pr = accs[rr] * ar[lane];
#pragma unroll
        for (int off = 32; off; off >>= 1) {
            pl += __shfl_xor(pl, off);
            pr += __shfl_xor(pr, off);
        }
        if (lane == 0) { el[row] = pl; er[row] = pr; }
    }
}

// ---------------------------------------------------------------------------
// K2: masked softmax rows + write attention. float4 IO.
// Block = one row i; adj row staged once as LDS bitmask, reused for all 8
// batches. Wave w handles batches {w, w+4}. Lane owns j = c*256 + lane*4 + q
// (c=0..7, q=0..3) -> float4 loads of er, float4 (1KB/wave) stores of attn.
// ---------------------------------------------------------------------------
__global__ __launch_bounds__(256) void k2_softmax(
    const int* __restrict__ adj, const float* __restrict__ el,
    const float* __restrict__ er, float* __restrict__ attn)
{
    __shared__ unsigned adjb[N_ / 32];
    int i = blockIdx.x;
    int tid = threadIdx.x, wave = tid >> 6, lane = tid & 63;

#pragma unroll
    for (int c = 0; c < 8; ++c) {
        int j = c * 256 + tid;
        unsigned long long msk = __ballot(adj[(size_t)i * N_ + j] > 0);
        if (lane == 0) {
            adjb[(j >> 5)]     = (unsigned)msk;
            adjb[(j >> 5) + 1] = (unsigned)(msk >> 32);
        }
    }
    __syncthreads();

    const float LOG2E = 1.44269504088896340736f;
#pragma unroll
    for (int bb = 0; bb < 2; ++bb) {
        int b = wave + bb * 4;
        float elv = el[(size_t)b * N_ + i];
        const float4* er4 = (const float4*)(er + (size_t)b * N_);
        float4* arow4 = (float4*)(attn + (size_t)b * N_ * N_ + (size_t)i * N_);

        float s[8][4];
        float m = -3.4e38f;
#pragma unroll
        for (int c = 0; c < 8; ++c) {
            float4 x4 = er4[c * 64 + lane];
            unsigned w = adjb[c * 8 + (lane >> 3)];
            int bb0 = (lane & 7) * 4;
            float xs[4] = {x4.x, x4.y, x4.z, x4.w};
#pragma unroll
            for (int q = 0; q < 4; ++q) {
                float x = elv + xs[q];
                x = fmaxf(x, ALPHA_ * x);              // leaky_relu, alpha<1
                unsigned bit = (w >> (bb0 + q)) & 1u;
                x = bit ? x : NEGINF_;
                s[c][q] = x;
                m = fmaxf(m, x);
            }
        }
#pragma unroll
        for (int off = 32; off; off >>= 1) m = fmaxf(m, __shfl_xor(m, off));

        float sum = 0.f;
#pragma unroll
        for (int c = 0; c < 8; ++c)
#pragma unroll
            for (int q = 0; q < 4; ++q) {
                float p = __builtin_amdgcn_exp2f((s[c][q] - m) * LOG2E);
                s[c][q] = p;
                sum += p;
            }
#pragma unroll
        for (int off = 32; off; off >>= 1) sum += __shfl_xor(sum, off);

        float inv = 1.0f / sum;
#pragma unroll
        for (int c = 0; c < 8; ++c) {
            float4 o;
            o.x = s[c][0] * inv; o.y = s[c][1] * inv;
            o.z = s[c][2] * inv; o.w = s[c][3] * inv;
            arow4[c * 64 + lane] = o;
        }
    }
}

// ---------------------------------------------------------------------------
// K3: h_out = attn @ h_prime, split-K over blockIdx.z (SPLIT_ segments of 512).
// Lane owns column o=lane; 16 rows/wave for register reuse of hp. attn loads
// are wave-uniform -> scalar loads. Partials to ws (or atomicAdd fallback).
// ---------------------------------------------------------------------------
template<bool ATOMIC>
__global__ __launch_bounds__(256) void k3_pv(
    const float* __restrict__ attn, const float* __restrict__ hp,
    float* __restrict__ outp)
{
    int tid = threadIdx.x;
    int wave = __builtin_amdgcn_readfirstlane(tid >> 6);
    int lane = tid & 63;
    int b = blockIdx.y;
    int split = blockIdx.z;
    int i0 = blockIdx.x * 64 + wave * 16;
    int kbase = split * KSEG_;

    const float* Ab  = attn + (size_t)b * N_ * N_;
    const float* hpb = hp + (size_t)b * N_ * FO_ + lane;

    float acc[16];
#pragma unroll
    for (int r = 0; r < 16; ++r) acc[r] = 0.f;

    float bv0[16], bv1[16];
#pragma unroll
    for (int kk = 0; kk < 16; ++kk) bv0[kk] = hpb[(size_t)(kbase + kk) * FO_];

#pragma unroll 1
    for (int k0 = kbase; k0 < kbase + KSEG_ - 32; k0 += 32) {
#pragma unroll
        for (int kk = 0; kk < 16; ++kk) bv1[kk] = hpb[(size_t)(k0 + 16 + kk) * FO_];
#pragma unroll
        for (int r = 0; r < 16; ++r) {
            const float* Ar = Ab + (size_t)(i0 + r) * N_ + k0;
#pragma unroll
            for (int kk = 0; kk < 16; ++kk) acc[r] = fmaf(Ar[kk], bv0[kk], acc[r]);
        }
#pragma unroll
        for (int kk = 0; kk < 16; ++kk) bv0[kk] = hpb[(size_t)(k0 + 32 + kk) * FO_];
#pragma unroll
        for (int r = 0; r < 16; ++r) {
            const float* Ar = Ab + (size_t)(i0 + r) * N_ + k0 + 16;
#pragma unroll
            for (int kk = 0; kk < 16; ++kk) acc[r] = fmaf(Ar[kk], bv1[kk], acc[r]);
        }
    }
    {   // tail chunk
        int k0 = kbase + KSEG_ - 32;
#pragma unroll
        for (int kk = 0; kk < 16; ++kk) bv1[kk] = hpb[(size_t)(k0 + 16 + kk) * FO_];
#pragma unroll
        for (int r = 0; r < 16; ++r) {
            const float* Ar = Ab + (size_t)(i0 + r) * N_ + k0;
#pragma unroll
            for (int kk = 0; kk < 16; ++kk) acc[r] = fmaf(Ar[kk], bv0[kk], acc[r]);
        }
#pragma unroll
        for (int r = 0; r < 16; ++r) {
            const float* Ar = Ab + (size_t)(i0 + r) * N_ + k0 + 16;
#pragma unroll
            for (int kk = 0; kk < 16; ++kk) acc[r] = fmaf(Ar[kk], bv1[kk], acc[r]);
        }
    }

    if (ATOMIC) {
        float* ob = outp + (size_t)b * N_ * FO_ + (size_t)i0 * FO_ + lane;
#pragma unroll
        for (int r = 0; r < 16; ++r) atomicAdd(&ob[(size_t)r * FO_], acc[r]);
    } else {
        float* ob = outp + (size_t)split * B_ * N_ * FO_
                  + (size_t)b * N_ * FO_ + (size_t)i0 * FO_ + lane;
#pragma unroll
        for (int r = 0; r < 16; ++r) ob[(size_t)r * FO_] = acc[r];
    }
}

// ---------------------------------------------------------------------------
// K4: hout = sum of SPLIT_ partials (float4).
// ---------------------------------------------------------------------------
__global__ __launch_bounds__(256) void k4_reduce(
    const float* __restrict__ part, float* __restrict__ hout)
{
    size_t i = (size_t)blockIdx.x * 256 + threadIdx.x;   // float4 index
    const size_t stride = (size_t)B_ * N_ * FO_ / 4;     // 262144
    const float4* p = (const float4*)part;
    float4 a = p[i];
    float4 b = p[i + stride];
    float4 c = p[i + 2 * stride];
    float4 d = p[i + 3 * stride];
    float4 o;
    o.x = (a.x + b.x) + (c.x + d.x);
    o.y = (a.y + b.y) + (c.y + d.y);
    o.z = (a.z + b.z) + (c.z + d.z);
    o.w = (a.w + b.w) + (c.w + d.w);
    ((float4*)hout)[i] = o;
}

// ---------------------------------------------------------------------------
extern "C" void kernel_launch(void* const* d_in, const int* in_sizes, int n_in,
                              void* d_out, int out_size, void* d_ws, size_t ws_size,
                              hipStream_t stream) {
    const float* h   = (const float*)d_in[0];
    const int*   adj = (const int*)d_in[1];
    const float* W   = (const float*)d_in[2];
    const float* a   = (const float*)d_in[3];

    float* hout = (float*)d_out;                                  // 8*2048*64
    float* attn = (float*)d_out + (size_t)B_ * N_ * FO_;          // 8*2048*2048

    const size_t hpN = (size_t)B_ * N_ * FO_;                     // 1,048,576
    float* hp   = (float*)d_ws;
    float* el   = hp + hpN;
    float* er   = el + (size_t)B_ * N_;
    float* part = er + (size_t)B_ * N_;
    const size_t need = (hpN + 2 * (size_t)B_ * N_ + (size_t)SPLIT_ * hpN) * sizeof(float);

    k1_hprime<<<1024, 256, 0, stream>>>(h, W, a, hp, el, er);
    k2_softmax<<<2048, 256, 0, stream>>>(adj, el, er, attn);

    if (ws_size >= need) {
        k3_pv<false><<<dim3(N_ / 64, B_, SPLIT_), 256, 0, stream>>>(attn, hp, part);
        k4_reduce<<<hpN / 4 / 256, 256, 0, stream>>>(part, hout);
    } else {
        hipMemsetAsync(hout, 0, hpN * sizeof(float), stream);
        k3_pv<true><<<dim3(N_ / 64, B_, SPLIT_), 256, 0, stream>>>(attn, hp, hout);
    }
}

// Round 4
// 226.708 us; speedup vs baseline: 3.0142x; 1.5996x over previous
//
#include <hip/hip_runtime.h>
#include <hip/hip_bf16.h>

#define B_ 8
#define N_ 2048
#define FIN_ 128
#define FO_ 64
#define ALPHA_ 0.2f
#define NEGINF_ -1000000000.0f
#define SPLIT_ 4
#define KSEG_ (N_ / SPLIT_)   // 512

typedef __attribute__((ext_vector_type(8))) short short8;
typedef __attribute__((ext_vector_type(4))) float f32x4;

// round-to-nearest-even f32 -> bf16 bits
__device__ __forceinline__ unsigned bf16_rne(float x) {
    union { float f; unsigned u; } v; v.f = x;
    return (v.u + 0x7FFFu + ((v.u >> 16) & 1u)) >> 16;
}
__device__ __forceinline__ float bf16_f32(unsigned b) {
    union { unsigned u; float f; } v; v.u = b << 16; return v.f;
}

// ---------------------------------------------------------------------------
// K1: h_prime = h @ W, plus e_l = h'·a_l, e_r = h'·a_r  (unchanged)
// ---------------------------------------------------------------------------
__global__ __launch_bounds__(256) void k1_hprime(
    const float* __restrict__ h, const float* __restrict__ W,
    const float* __restrict__ a, float* __restrict__ hp,
    float* __restrict__ el, float* __restrict__ er)
{
    __shared__ float Wl[FIN_ * FO_];
    __shared__ float al[FO_], ar[FO_];
    __shared__ float hrow[4][4][FIN_];

    int tid = threadIdx.x;
    const float4* W4 = (const float4*)W;
    float4* Wl4 = (float4*)Wl;
#pragma unroll
    for (int i = 0; i < 8; ++i) Wl4[tid + 256 * i] = W4[tid + 256 * i];
    if (tid < FO_) { al[tid] = a[tid]; ar[tid] = a[FO_ + tid]; }

    int wave = tid >> 6, lane = tid & 63;
    int row0 = blockIdx.x * 16 + wave * 4;
#pragma unroll
    for (int rr = 0; rr < 4; ++rr) {
        hrow[wave][rr][lane]      = h[(size_t)(row0 + rr) * FIN_ + lane];
        hrow[wave][rr][lane + 64] = h[(size_t)(row0 + rr) * FIN_ + lane + 64];
    }
    __syncthreads();

    float acc0 = 0.f, acc1 = 0.f, acc2 = 0.f, acc3 = 0.f;
#pragma unroll 8
    for (int k = 0; k < FIN_; ++k) {
        float w = Wl[k * FO_ + lane];
        acc0 = fmaf(hrow[wave][0][k], w, acc0);
        acc1 = fmaf(hrow[wave][1][k], w, acc1);
        acc2 = fmaf(hrow[wave][2][k], w, acc2);
        acc3 = fmaf(hrow[wave][3][k], w, acc3);
    }

    float accs[4] = {acc0, acc1, acc2, acc3};
#pragma unroll
    for (int rr = 0; rr < 4; ++rr) {
        int row = row0 + rr;
        hp[(size_t)row * FO_ + lane] = accs[rr];
        float pl = accs[rr] * al[lane];
        float pr = accs[rr] * ar[lane];
#pragma unroll
        for (int off = 32; off; off >>= 1) {
            pl += __shfl_xor(pl, off);
            pr += __shfl_xor(pr, off);
        }
        if (lane == 0) { el[row] = pl; er[row] = pr; }
    }
}

// ---------------------------------------------------------------------------
// K2: masked softmax rows + write attention. float4 IO.  (unchanged)
// ---------------------------------------------------------------------------
__global__ __launch_bounds__(256) void k2_softmax(
    const int* __restrict__ adj, const float* __restrict__ el,
    const float* __restrict__ er, float* __restrict__ attn)
{
    __shared__ unsigned adjb[N_ / 32];
    int i = blockIdx.x;
    int tid = threadIdx.x, wave = tid >> 6, lane = tid & 63;

#pragma unroll
    for (int c = 0; c < 8; ++c) {
        int j = c * 256 + tid;
        unsigned long long msk = __ballot(adj[(size_t)i * N_ + j] > 0);
        if (lane == 0) {
            adjb[(j >> 5)]     = (unsigned)msk;
            adjb[(j >> 5) + 1] = (unsigned)(msk >> 32);
        }
    }
    __syncthreads();

    const float LOG2E = 1.44269504088896340736f;
#pragma unroll
    for (int bb = 0; bb < 2; ++bb) {
        int b = wave + bb * 4;
        float elv = el[(size_t)b * N_ + i];
        const float4* er4 = (const float4*)(er + (size_t)b * N_);
        float4* arow4 = (float4*)(attn + (size_t)b * N_ * N_ + (size_t)i * N_);

        float s[8][4];
        float m = -3.4e38f;
#pragma unroll
        for (int c = 0; c < 8; ++c) {
            float4 x4 = er4[c * 64 + lane];
            unsigned w = adjb[c * 8 + (lane >> 3)];
            int bb0 = (lane & 7) * 4;
            float xs[4] = {x4.x, x4.y, x4.z, x4.w};
#pragma unroll
            for (int q = 0; q < 4; ++q) {
                float x = elv + xs[q];
                x = fmaxf(x, ALPHA_ * x);
                unsigned bit = (w >> (bb0 + q)) & 1u;
                x = bit ? x : NEGINF_;
                s[c][q] = x;
                m = fmaxf(m, x);
            }
        }
#pragma unroll
        for (int off = 32; off; off >>= 1) m = fmaxf(m, __shfl_xor(m, off));

        float sum = 0.f;
#pragma unroll
        for (int c = 0; c < 8; ++c)
#pragma unroll
            for (int q = 0; q < 4; ++q) {
                float p = __builtin_amdgcn_exp2f((s[c][q] - m) * LOG2E);
                s[c][q] = p;
                sum += p;
            }
#pragma unroll
        for (int off = 32; off; off >>= 1) sum += __shfl_xor(sum, off);

        float inv = 1.0f / sum;
#pragma unroll
        for (int c = 0; c < 8; ++c) {
            float4 o;
            o.x = s[c][0] * inv; o.y = s[c][1] * inv;
            o.z = s[c][2] * inv; o.w = s[c][3] * inv;
            arow4[c * 64 + lane] = o;
        }
    }
}

// ---------------------------------------------------------------------------
// K3: h_out = attn @ h_prime via MFMA 16x16x32 bf16, double-bf16 (hi/lo)
// decomposition: A·B ~= Ahi·Bhi + Ahi·Blo + Alo·Bhi  (err ~2^-17).
// No LDS, no barriers. Block = 64 rows x 64 cols, 4 waves, one 16-row strip
// each. Split-K over blockIdx.z. Layouts (m89-verified family):
//   A frag: row = lane&15, k = (lane>>4)*8 + j   (8 consecutive k = 32B read)
//   B frag: col = lane&15, k = (lane>>4)*8 + j   (imm-offset dword loads)
//   D:      col = lane&15, row = (lane>>4)*4 + r
// ---------------------------------------------------------------------------
template<bool ATOMIC>
__global__ __launch_bounds__(256) void k3_mfma(
    const float* __restrict__ attn, const float* __restrict__ hp,
    float* __restrict__ outp)
{
    int tid  = threadIdx.x;
    int wave = __builtin_amdgcn_readfirstlane(tid >> 6);
    int lane = tid & 63;
    int l15 = lane & 15, lg = lane >> 4;
    int b = blockIdx.y, split = blockIdx.z;
    int i0w = blockIdx.x * 64 + wave * 16;
    int kbase = split * KSEG_;

    const float* Ap = attn + (size_t)b * N_ * N_ + (size_t)(i0w + l15) * N_
                    + kbase + lg * 8;
    const float* Bp = hp + (size_t)b * N_ * FO_ + (size_t)(kbase + lg * 8) * FO_ + l15;

    f32x4 acc[4];
#pragma unroll
    for (int c = 0; c < 4; ++c) acc[c] = (f32x4){0.f, 0.f, 0.f, 0.f};

#pragma unroll 2
    for (int s = 0; s < KSEG_ / 32; ++s) {
        float4 a0 = *(const float4*)Ap;
        float4 a1 = *(const float4*)(Ap + 4);
        float av[8] = {a0.x, a0.y, a0.z, a0.w, a1.x, a1.y, a1.z, a1.w};
        short8 ahi, alo;
#pragma unroll
        for (int j = 0; j < 8; ++j) {
            unsigned hb = bf16_rne(av[j]);
            ahi[j] = (short)hb;
            alo[j] = (short)bf16_rne(av[j] - bf16_f32(hb));
        }
#pragma unroll
        for (int c = 0; c < 4; ++c) {
            short8 bhi, blo;
#pragma unroll
            for (int j = 0; j < 8; ++j) {
                float x = Bp[c * 16 + (size_t)j * FO_];
                unsigned hb = bf16_rne(x);
                bhi[j] = (short)hb;
                blo[j] = (short)bf16_rne(x - bf16_f32(hb));
            }
            acc[c] = __builtin_amdgcn_mfma_f32_16x16x32_bf16(ahi, bhi, acc[c], 0, 0, 0);
            acc[c] = __builtin_amdgcn_mfma_f32_16x16x32_bf16(ahi, blo, acc[c], 0, 0, 0);
            acc[c] = __builtin_amdgcn_mfma_f32_16x16x32_bf16(alo, bhi, acc[c], 0, 0, 0);
        }
        Ap += 32;
        Bp += 32 * FO_;
    }

    if (ATOMIC) {
        float* ob = outp + (size_t)b * N_ * FO_;
#pragma unroll
        for (int c = 0; c < 4; ++c)
#pragma unroll
            for (int r = 0; r < 4; ++r)
                atomicAdd(&ob[(size_t)(i0w + lg * 4 + r) * FO_ + c * 16 + l15],
                          acc[c][r]);
    } else {
        float* ob = outp + (size_t)split * B_ * N_ * FO_ + (size_t)b * N_ * FO_;
#pragma unroll
        for (int c = 0; c < 4; ++c)
#pragma unroll
            for (int r = 0; r < 4; ++r)
                ob[(size_t)(i0w + lg * 4 + r) * FO_ + c * 16 + l15] = acc[c][r];
    }
}

// ---------------------------------------------------------------------------
// K4: hout = sum of SPLIT_ partials (float4).  (unchanged)
// ---------------------------------------------------------------------------
__global__ __launch_bounds__(256) void k4_reduce(
    const float* __restrict__ part, float* __restrict__ hout)
{
    size_t i = (size_t)blockIdx.x * 256 + threadIdx.x;
    const size_t stride = (size_t)B_ * N_ * FO_ / 4;
    const float4* p = (const float4*)part;
    float4 a = p[i];
    float4 b = p[i + stride];
    float4 c = p[i + 2 * stride];
    float4 d = p[i + 3 * stride];
    float4 o;
    o.x = (a.x + b.x) + (c.x + d.x);
    o.y = (a.y + b.y) + (c.y + d.y);
    o.z = (a.z + b.z) + (c.z + d.z);
    o.w = (a.w + b.w) + (c.w + d.w);
    ((float4*)hout)[i] = o;
}

// ---------------------------------------------------------------------------
extern "C" void kernel_launch(void* const* d_in, const int* in_sizes, int n_in,
                              void* d_out, int out_size, void* d_ws, size_t ws_size,
                              hipStream_t stream) {
    const float* h   = (const float*)d_in[0];
    const int*   adj = (const int*)d_in[1];
    const float* W   = (const float*)d_in[2];
    const float* a   = (const float*)d_in[3];

    float* hout = (float*)d_out;                                  // 8*2048*64
    float* attn = (float*)d_out + (size_t)B_ * N_ * FO_;          // 8*2048*2048

    const size_t hpN = (size_t)B_ * N_ * FO_;                     // 1,048,576
    float* hp   = (float*)d_ws;
    float* el   = hp + hpN;
    float* er   = el + (size_t)B_ * N_;
    float* part = er + (size_t)B_ * N_;
    const size_t need = (hpN + 2 * (size_t)B_ * N_ + (size_t)SPLIT_ * hpN) * sizeof(float);

    k1_hprime<<<1024, 256, 0, stream>>>(h, W, a, hp, el, er);
    k2_softmax<<<2048, 256, 0, stream>>>(adj, el, er, attn);

    if (ws_size >= need) {
        k3_mfma<false><<<dim3(N_ / 64, B_, SPLIT_), 256, 0, stream>>>(attn, hp, part);
        k4_reduce<<<hpN / 4 / 256, 256, 0, stream>>>(part, hout);
    } else {
        hipMemsetAsync(hout, 0, hpN * sizeof(float), stream);
        k3_mfma<true><<<dim3(N_ / 64, B_, SPLIT_), 256, 0, stream>>>(attn, hp, hout);
    }
}

// Round 5
// 222.263 us; speedup vs baseline: 3.0745x; 1.0200x over previous
//
#include <hip/hip_runtime.h>
#include <hip/hip_bf16.h>

#define B_ 8
#define N_ 2048
#define FIN_ 128
#define FO_ 64
#define ALPHA_ 0.2f
#define NEGINF_ -1000000000.0f

typedef __attribute__((ext_vector_type(8))) short short8;
typedef __attribute__((ext_vector_type(4))) float f32x4;

// round-to-nearest-even f32 -> bf16 bits, and back
__device__ __forceinline__ unsigned bf16_rne(float x) {
    union { float f; unsigned u; } v; v.f = x;
    return (v.u + 0x7FFFu + ((v.u >> 16) & 1u)) >> 16;
}
__device__ __forceinline__ float bf16_f32(unsigned b) {
    union { unsigned u; float f; } v; v.u = b << 16; return v.f;
}
// split two f32 into packed bf16 hi-word and lo-(residual)-word
__device__ __forceinline__ void split2(float x0, float x1, unsigned& hw, unsigned& lw) {
    unsigned h0 = bf16_rne(x0), h1 = bf16_rne(x1);
    unsigned l0 = bf16_rne(x0 - bf16_f32(h0));
    unsigned l1 = bf16_rne(x1 - bf16_f32(h1));
    hw = h0 | (h1 << 16);
    lw = l0 | (l1 << 16);
}

// ---------------------------------------------------------------------------
// K0: adj (int32 NxN) -> packed bitmask (uint32 N x 64). Read once: 16.8 MB.
// ---------------------------------------------------------------------------
__global__ __launch_bounds__(256) void k0_bits(
    const int* __restrict__ adj, unsigned* __restrict__ bits)
{
    int i = blockIdx.x, tid = threadIdx.x, lane = tid & 63;
#pragma unroll
    for (int c = 0; c < 8; ++c) {
        int j = c * 256 + tid;
        unsigned long long m = __ballot(adj[(size_t)i * N_ + j] > 0);
        if (lane == 0) {
            bits[(size_t)i * 64 + (j >> 5)]     = (unsigned)m;
            bits[(size_t)i * 64 + (j >> 5) + 1] = (unsigned)(m >> 32);
        }
    }
}

// ---------------------------------------------------------------------------
// K1: h_prime = h @ W (compute unchanged); epilogue writes hpT as bf16 hi/lo
// TRANSPOSED [b][o][k] (via LDS transpose) for the fused kernel's B-frags,
// plus e_l / e_r reductions.
// ---------------------------------------------------------------------------
__global__ __launch_bounds__(256) void k1_hprime(
    const float* __restrict__ h, const float* __restrict__ W,
    const float* __restrict__ a,
    unsigned short* __restrict__ hpTh, unsigned short* __restrict__ hpTl,
    float* __restrict__ el, float* __restrict__ er)
{
    __shared__ float Wl[FIN_ * FO_];
    __shared__ float al[FO_], ar[FO_];
    __shared__ float hrow[4][4][FIN_];
    __shared__ float tr[FO_][17];          // [o][k_local], padded

    int tid = threadIdx.x;
    const float4* W4 = (const float4*)W;
    float4* Wl4 = (float4*)Wl;
#pragma unroll
    for (int i = 0; i < 8; ++i) Wl4[tid + 256 * i] = W4[tid + 256 * i];
    if (tid < FO_) { al[tid] = a[tid]; ar[tid] = a[FO_ + tid]; }

    int wave = tid >> 6, lane = tid & 63;
    int row0 = blockIdx.x * 16 + wave * 4;
#pragma unroll
    for (int rr = 0; rr < 4; ++rr) {
        hrow[wave][rr][lane]      = h[(size_t)(row0 + rr) * FIN_ + lane];
        hrow[wave][rr][lane + 64] = h[(size_t)(row0 + rr) * FIN_ + lane + 64];
    }
    __syncthreads();

    float acc0 = 0.f, acc1 = 0.f, acc2 = 0.f, acc3 = 0.f;
#pragma unroll 8
    for (int k = 0; k < FIN_; ++k) {
        float w = Wl[k * FO_ + lane];
        acc0 = fmaf(hrow[wave][0][k], w, acc0);
        acc1 = fmaf(hrow[wave][1][k], w, acc1);
        acc2 = fmaf(hrow[wave][2][k], w, acc2);
        acc3 = fmaf(hrow[wave][3][k], w, acc3);
    }

    float accs[4] = {acc0, acc1, acc2, acc3};
#pragma unroll
    for (int rr = 0; rr < 4; ++rr) {
        int row = row0 + rr;
        tr[lane][wave * 4 + rr] = accs[rr];
        float pl = accs[rr] * al[lane];
        float pr = accs[rr] * ar[lane];
#pragma unroll
        for (int off = 32; off; off >>= 1) {
            pl += __shfl_xor(pl, off);
            pr += __shfl_xor(pr, off);
        }
        if (lane == 0) { el[row] = pl; er[row] = pr; }
    }
    __syncthreads();

    // transpose-out: thread t -> (o = t>>2, kq = t&3), 4 k each, bf16 hi/lo
    int o = tid >> 2, kq = tid & 3;
    int gk0 = (blockIdx.x * 16) & (N_ - 1);
    int bb  = (blockIdx.x * 16) >> 11;
    float x0 = tr[o][kq * 4 + 0], x1 = tr[o][kq * 4 + 1];
    float x2 = tr[o][kq * 4 + 2], x3 = tr[o][kq * 4 + 3];
    unsigned hw0, lw0, hw1, lw1;
    split2(x0, x1, hw0, lw0);
    split2(x2, x3, hw1, lw1);
    size_t base = ((size_t)bb * FO_ + o) * N_ + gk0 + kq * 4;
    uint2 H = {hw0, hw1}, L = {lw0, lw1};
    *(uint2*)&hpTh[base] = H;
    *(uint2*)&hpTl[base] = L;
}

// ---------------------------------------------------------------------------
// K23: fused masked-softmax + attention store + PV MFMA.
// Block = (16 rows, 1 batch). Phase A: row sums (no max-sub; masked -> exp
// underflow 0). Phase B: wave w owns k in [w*512,(w+1)*512): compute P,
// float4-store attn, bf16 hi/lo split -> same-wave LDS transpose -> 3-term
// MFMA vs hpT. Cross-wave reduce -> hout.
// ---------------------------------------------------------------------------
__global__ __launch_bounds__(256, 4) void k23_fused(
    const unsigned* __restrict__ bits, const float* __restrict__ el,
    const float* __restrict__ er,
    const unsigned short* __restrict__ hpTh, const unsigned short* __restrict__ hpTl,
    float* __restrict__ attn, float* __restrict__ hout)
{
    __shared__ alignas(16) float erb[N_];            // 8 KB
    __shared__ unsigned adjw[16 * 65];               // padded rows
    __shared__ float el16[16], inv16[16];
    __shared__ alignas(16) unsigned short Pt[4][16][40];  // per-wave hi tile
    __shared__ alignas(16) unsigned short Pl[4][16][40];  // per-wave lo tile
    __shared__ float red[4][16][FO_];                // 16 KB

    int tid = threadIdx.x;
    int wave = tid >> 6, lane = tid & 63;
    int i0 = blockIdx.x * 16;
    int b  = blockIdx.y;

    // stage er row for batch b (8 KB) and 16 rows of mask words (4 KB)
    const float4* erg = (const float4*)(er + (size_t)b * N_);
    float4* erb4 = (float4*)erb;
    erb4[tid]       = erg[tid];
    erb4[tid + 256] = erg[tid + 256];
#pragma unroll
    for (int q = 0; q < 4; ++q) {
        int idx = q * 256 + tid;                      // 0..1023
        adjw[(idx >> 6) * 65 + (idx & 63)] =
            bits[(size_t)(i0 + (idx >> 6)) * 64 + (idx & 63)];
    }
    if (tid < 16) el16[tid] = el[(size_t)b * N_ + i0 + tid];
    __syncthreads();

    const float LOG2E = 1.44269504088896340736f;

    // ---- Phase A: per-row sum of exp(leaky(el+er)) over masked j ----------
    float4 ercache[8];
#pragma unroll
    for (int c = 0; c < 8; ++c) ercache[c] = erb4[c * 64 + lane];

#pragma unroll
    for (int rr = 0; rr < 4; ++rr) {
        int r = wave * 4 + rr;
        float elv = el16[r];
        float sum = 0.f;
#pragma unroll
        for (int c = 0; c < 8; ++c) {
            unsigned w = adjw[r * 65 + c * 8 + (lane >> 3)];
            int b0 = (lane & 7) * 4;
            float xs[4] = {ercache[c].x, ercache[c].y, ercache[c].z, ercache[c].w};
#pragma unroll
            for (int q = 0; q < 4; ++q) {
                float x = elv + xs[q];
                x = fmaxf(x, ALPHA_ * x);
                x = ((w >> (b0 + q)) & 1u) ? x : NEGINF_;
                sum += __builtin_amdgcn_exp2f(x * LOG2E);
            }
        }
#pragma unroll
        for (int off = 32; off; off >>= 1) sum += __shfl_xor(sum, off);
        if (lane == 0) inv16[r] = 1.0f / sum;
    }
    __syncthreads();

    // ---- Phase B: P + attn store + PV ------------------------------------
    int l15 = lane & 15, lg = lane >> 4;
    int prow = lane >> 2;        // row this lane computes P for
    int pj4  = lane & 3;         // j-quad within 16
    float pel  = el16[prow];
    float pinv = inv16[prow];
    int kbase = wave * (N_ / 4); // 512 k per wave

    float* attnb = attn + (size_t)b * N_ * N_;
    const unsigned short* Bh = hpTh + (size_t)b * FO_ * N_;
    const unsigned short* Bl = hpTl + (size_t)b * FO_ * N_;
    unsigned short* PtW = &Pt[wave][0][0];
    unsigned short* PlW = &Pl[wave][0][0];

    f32x4 acc[4];
#pragma unroll
    for (int c = 0; c < 4; ++c) acc[c] = (f32x4){0.f, 0.f, 0.f, 0.f};

#pragma unroll 1
    for (int ks = kbase; ks < kbase + N_ / 4; ks += 32) {
        // B-fragments (independent of P) — issue loads early
        short8 bhi[4], blo[4];
#pragma unroll
        for (int c = 0; c < 4; ++c) {
            size_t boff = (size_t)(c * 16 + l15) * N_ + ks + lg * 8;
            bhi[c] = *(const short8*)&Bh[boff];
            blo[c] = *(const short8*)&Bl[boff];
        }

        // compute 8 P values: j = ks + pj4*4 + q  and  j = ks + 16 + pj4*4 + q
        float4 e0 = erb4[(ks >> 2) + pj4];
        float4 e1 = erb4[(ks >> 2) + 4 + pj4];
        unsigned mw = adjw[prow * 65 + (ks >> 5)];
        int bq = pj4 * 4;
        float e0a[4] = {e0.x, e0.y, e0.z, e0.w};
        float e1a[4] = {e1.x, e1.y, e1.z, e1.w};
        float p0[4], p1[4];
#pragma unroll
        for (int q = 0; q < 4; ++q) {
            float x = pel + e0a[q];
            x = fmaxf(x, ALPHA_ * x);
            x = ((mw >> (bq + q)) & 1u) ? x : NEGINF_;
            p0[q] = __builtin_amdgcn_exp2f(x * LOG2E) * pinv;
            float y = pel + e1a[q];
            y = fmaxf(y, ALPHA_ * y);
            y = ((mw >> (16 + bq + q)) & 1u) ? y : NEGINF_;
            p1[q] = __builtin_amdgcn_exp2f(y * LOG2E) * pinv;
        }

        // attention store (written once, never re-read)
        size_t arow = (size_t)(i0 + prow) * N_ + ks;
        float4 s0 = {p0[0], p0[1], p0[2], p0[3]};
        float4 s1 = {p1[0], p1[1], p1[2], p1[3]};
        *(float4*)&attnb[arow + bq]      = s0;
        *(float4*)&attnb[arow + 16 + bq] = s1;

        // bf16 hi/lo -> per-wave LDS tile (same-wave, DS in-order, no barrier)
        unsigned hw0, lw0, hw1, lw1, hw2, lw2, hw3, lw3;
        split2(p0[0], p0[1], hw0, lw0); split2(p0[2], p0[3], hw1, lw1);
        split2(p1[0], p1[1], hw2, lw2); split2(p1[2], p1[3], hw3, lw3);
        uint2 H0 = {hw0, hw1}, H1 = {hw2, hw3}, L0 = {lw0, lw1}, L1 = {lw2, lw3};
        *(uint2*)&PtW[prow * 40 + bq]      = H0;
        *(uint2*)&PtW[prow * 40 + 16 + bq] = H1;
        *(uint2*)&PlW[prow * 40 + bq]      = L0;
        *(uint2*)&PlW[prow * 40 + 16 + bq] = L1;

        // A-fragments: row = l15, k = lg*8..+7 (transposed read)
        short8 ahi = *(const short8*)&PtW[l15 * 40 + lg * 8];
        short8 alo = *(const short8*)&PlW[l15 * 40 + lg * 8];

#pragma unroll
        for (int c = 0; c < 4; ++c) {
            acc[c] = __builtin_amdgcn_mfma_f32_16x16x32_bf16(ahi, bhi[c], acc[c], 0, 0, 0);
            acc[c] = __builtin_amdgcn_mfma_f32_16x16x32_bf16(ahi, blo[c], acc[c], 0, 0, 0);
            acc[c] = __builtin_amdgcn_mfma_f32_16x16x32_bf16(alo, bhi[c], acc[c], 0, 0, 0);
        }
    }

    // cross-wave reduction of 16x64 tiles
#pragma unroll
    for (int c = 0; c < 4; ++c)
#pragma unroll
        for (int r = 0; r < 4; ++r)
            red[wave][lg * 4 + r][c * 16 + l15] = acc[c][r];
    __syncthreads();

    int oo = tid & 63;
    int ib = tid >> 6;
#pragma unroll
    for (int q = 0; q < 4; ++q) {
        int i = ib * 4 + q;
        float s = (red[0][i][oo] + red[1][i][oo]) + (red[2][i][oo] + red[3][i][oo]);
        hout[((size_t)b * N_ + i0 + i) * FO_ + oo] = s;
    }
}

// ---------------------------------------------------------------------------
extern "C" void kernel_launch(void* const* d_in, const int* in_sizes, int n_in,
                              void* d_out, int out_size, void* d_ws, size_t ws_size,
                              hipStream_t stream) {
    const float* h   = (const float*)d_in[0];
    const int*   adj = (const int*)d_in[1];
    const float* W   = (const float*)d_in[2];
    const float* a   = (const float*)d_in[3];

    float* hout = (float*)d_out;                              // 8*2048*64
    float* attn = (float*)d_out + (size_t)B_ * N_ * FO_;      // 8*2048*2048

    const size_t hpN = (size_t)B_ * FO_ * N_;                 // 1,048,576
    unsigned short* hpTh = (unsigned short*)d_ws;
    unsigned short* hpTl = hpTh + hpN;
    float* elw = (float*)(hpTl + hpN);
    float* erw = elw + (size_t)B_ * N_;
    unsigned* bits = (unsigned*)(erw + (size_t)B_ * N_);      // 2048*64 u32

    k0_bits<<<N_, 256, 0, stream>>>(adj, bits);
    k1_hprime<<<(B_ * N_) / 16, 256, 0, stream>>>(h, W, a, hpTh, hpTl, elw, erw);
    k23_fused<<<dim3(N_ / 16, B_), 256, 0, stream>>>(bits, elw, erw, hpTh, hpTl, attn, hout);
}